// Round 7
// baseline (278.221 us; speedup 1.0000x reference)
//
#include <hip/hip_runtime.h>

#define D_MODEL 1024
#define T_SEQ   1024
#define BATCH   8
#define NHEAD   16
#define HDIM    64

typedef float      v4f   __attribute__((ext_vector_type(4)));
typedef _Float16   half8 __attribute__((ext_vector_type(8)));
typedef _Float16   half4h __attribute__((ext_vector_type(4)));
typedef unsigned int ui4 __attribute__((ext_vector_type(4)));

// async global->LDS, 16B per lane, dest = wave-uniform base + lane*16
__device__ __forceinline__ void load_lds16(const _Float16* g, _Float16* l) {
  __builtin_amdgcn_global_load_lds(
      (const __attribute__((address_space(1))) unsigned int*)g,
      (__attribute__((address_space(3))) unsigned int*)l, 16, 0, 0);
}

// ---------------- LayerNorm (fp32 in) -> fp16 xn ----------------
__global__ __launch_bounds__(256) void ln_kernel(const float* __restrict__ x,
                                                 const float* __restrict__ gamma,
                                                 const float* __restrict__ beta,
                                                 _Float16* __restrict__ xn) {
  int row = blockIdx.x;
  int tid = threadIdx.x;
  const float* xr = x + (size_t)row * D_MODEL;
  v4f xv = *(const v4f*)(xr + tid * 4);
  float s  = xv[0] + xv[1] + xv[2] + xv[3];
  float sq = xv[0]*xv[0] + xv[1]*xv[1] + xv[2]*xv[2] + xv[3]*xv[3];
#pragma unroll
  for (int off = 32; off > 0; off >>= 1) {
    s  += __shfl_xor(s, off);
    sq += __shfl_xor(sq, off);
  }
  __shared__ float ps[4], psq[4];
  int wave = tid >> 6;
  if ((tid & 63) == 0) { ps[wave] = s; psq[wave] = sq; }
  __syncthreads();
  float tot  = ps[0] + ps[1] + ps[2] + ps[3];
  float totq = psq[0] + psq[1] + psq[2] + psq[3];
  float mean = tot * (1.0f / D_MODEL);
  float var  = totq * (1.0f / D_MODEL) - mean * mean;
  float rs   = rsqrtf(var + 1e-5f);
  v4f gv = *(const v4f*)(gamma + tid * 4);
  v4f bv = *(const v4f*)(beta + tid * 4);
  half4h o;
#pragma unroll
  for (int i = 0; i < 4; ++i)
    o[i] = (_Float16)((xv[i] - mean) * rs * gv[i] + bv[i]);
  *(half4h*)(xn + (size_t)row * D_MODEL + tid * 4) = o;
}

// ------- fragize weights: W (K x N fp32) -> Bfrag[nt][kt][lane][8] fp16 -------
__global__ __launch_bounds__(256) void fragize_kernel(const float* __restrict__ W,
                                                      _Float16* __restrict__ Bf,
                                                      int N, int K) {
  int g = blockIdx.x * 256 + threadIdx.x;
  int lane = g & 63, tile = g >> 6;
  int ktiles = K >> 5;
  int kt = tile % ktiles, nt = tile / ktiles;
  int n  = nt * 16 + (lane & 15);
  int k0 = kt * 32 + (lane >> 4) * 8;
  half8 o;
#pragma unroll
  for (int j = 0; j < 8; ++j) o[j] = (_Float16)W[(size_t)(k0 + j) * N + n];
  *(half8*)(Bf + (size_t)g * 8) = o;
}

// ------- fragize activations: X (M x 1024 fp16, row-major) -> Afrag[mt][kt][lane][8] ---
// A-frag: lane holds A[m = lane&15][k = (lane>>4)*8 + j]; flat tile g = mt*32 + kt
__global__ __launch_bounds__(256) void afrag_kernel(const _Float16* __restrict__ X,
                                                    _Float16* __restrict__ Af) {
  int g = blockIdx.x * 4 + (threadIdx.x >> 6);
  int lane = threadIdx.x & 63;
  int mt = g >> 5, kt = g & 31;
  half8 v = *(const half8*)(X + (size_t)(mt * 16 + (lane & 15)) * 1024 + kt * 32 + (lane >> 4) * 8);
  *(half8*)(Af + ((size_t)g * 64 + lane) * 8) = v;
}

// ------- batched transpose: Vd (P,1024,64) -> Vt (P,64,1024), fp16 -------
__global__ __launch_bounds__(256) void vtrans_kernel(const _Float16* __restrict__ Vd,
                                                     _Float16* __restrict__ Vt) {
  __shared__ _Float16 tile[64][68];
  int p  = blockIdx.y;
  int t0 = blockIdx.x * 64;
  int tid = threadIdx.x;
  int r = tid >> 3, c = (tid & 7) * 8;
#pragma unroll
  for (int it = 0; it < 2; ++it) {
    int rr = r + it * 32;
    *(ui4*)&tile[rr][c] = *(const ui4*)&Vd[((size_t)p * T_SEQ + t0 + rr) * HDIM + c];
  }
  __syncthreads();
#pragma unroll
  for (int it = 0; it < 2; ++it) {
    int d = r + it * 32;
    half8 o;
#pragma unroll
    for (int j = 0; j < 8; ++j) o[j] = tile[c + j][d];
    *(half8*)&Vt[((size_t)p * HDIM + d) * T_SEQ + t0 + c] = o;
  }
}

// ------- 128x128 MFMA GEMM, BARRIER-FREE: A-frags and B-frags streamed from global ----
// Ping-pong register prefetch; no LDS, no __syncthreads in the K-loop.
// MODE 0: epilogue -> Q(B,H,T,64)*(0.125*log2e), K(B,H,T,64), V(B,H,T,64)
// MODE 1: epilogue -> fp32 out + bias
template <int MODE>
__global__ __launch_bounds__(256) void gemm_kernel(
    const _Float16* __restrict__ Af, const _Float16* __restrict__ Bf,
    const float* __restrict__ bias, int M, int N, int K,
    float* __restrict__ outF,
    _Float16* __restrict__ Qd, _Float16* __restrict__ Kd, _Float16* __restrict__ Vd) {
  int tid = threadIdx.x;
  int wave = tid >> 6, lane = tid & 63;
  int l15 = lane & 15, quad = lane >> 4;
  int wm = (wave & 1) * 64, wn = (wave >> 1) * 64;
  int m0 = blockIdx.x * 128, n0 = blockIdx.y * 128;   // x = M fast: residents share B panel
  const int ktiles = K >> 5;
  const size_t fstr = (size_t)ktiles * 512;           // stride between 16-row frag tiles
  const _Float16* Ap = Af + (size_t)((m0 + wm) >> 4) * fstr + lane * 8;
  const _Float16* Bp = Bf + (size_t)((n0 + wn) >> 4) * fstr + lane * 8;
  v4f zero = {0.f, 0.f, 0.f, 0.f};
  v4f acc[4][4];
#pragma unroll
  for (int i = 0; i < 4; ++i)
#pragma unroll
    for (int j = 0; j < 4; ++j) acc[i][j] = zero;

  half8 aa[2][4], bb[2][4];
  auto LOAD = [&](int s, int kt) {
#pragma unroll
    for (int i = 0; i < 4; ++i) {
      aa[s][i] = *(const half8*)(Ap + i * fstr + (size_t)kt * 512);
      bb[s][i] = *(const half8*)(Bp + i * fstr + (size_t)kt * 512);
    }
  };
  auto MFMA = [&](int s) {
#pragma unroll
    for (int mi = 0; mi < 4; ++mi)
#pragma unroll
      for (int ni = 0; ni < 4; ++ni)
        acc[mi][ni] = __builtin_amdgcn_mfma_f32_16x16x32_f16(aa[s][mi], bb[s][ni], acc[mi][ni], 0, 0, 0);
  };
  LOAD(0, 0);
  for (int kt = 0; kt < ktiles; kt += 2) {
    LOAD(1, kt + 1);
    MFMA(0);
    if (kt + 2 < ktiles) LOAD(0, kt + 2);
    MFMA(1);
  }
  // epilogue: C layout row=quad*4+r, col=l15
  float bv[4];
#pragma unroll
  for (int ni = 0; ni < 4; ++ni) bv[ni] = bias[n0 + wn + ni * 16 + l15];
#pragma unroll
  for (int mi = 0; mi < 4; ++mi) {
#pragma unroll
    for (int ni = 0; ni < 4; ++ni) {
      int n = n0 + wn + ni * 16 + l15;
#pragma unroll
      for (int r = 0; r < 4; ++r) {
        int m = m0 + wm + mi * 16 + quad * 4 + r;
        float v = acc[mi][ni][r] + bv[ni];
        if (MODE == 1) {
          outF[(size_t)m * N + n] = v;
        } else {
          int b = m >> 10, t = m & 1023;
          int h = (n >> 6) & 15, d = n & 63;
          size_t idx = ((size_t)(b * NHEAD + h) * T_SEQ + t) * HDIM + d;
          // 0.125 * log2(e): softmax runs in exp2 domain
          if (n < 1024)        Qd[idx] = (_Float16)(v * 0.18033688f);
          else if (n < 2048)   Kd[idx] = (_Float16)v;
          else                 Vd[idx] = (_Float16)v;
        }
      }
    }
  }
}

// ------- flash attention, S^T formulation: 64 q-rows/block (4 waves), 64-key tiles ------
// S^T = K Q^T: lane owns ONE q-row (col=l15), 16 keys in regs. O^T = V^T P^T.
// Epilogue emits output directly in A-frag layout for the out-proj GEMM.
__global__ __launch_bounds__(256) void attn_kernel(const _Float16* __restrict__ Qg,
                                                   const _Float16* __restrict__ Kk,
                                                   const _Float16* __restrict__ Vt,
                                                   const int* __restrict__ x_lens,
                                                   _Float16* __restrict__ Afatt) {
  __shared__ _Float16 Ks[2][64 * 32];   // [d-half][key*32 + chunk]
  __shared__ _Float16 Vs[2][64 * 32];   // [key-half][d*32 + chunk]
  __shared__ _Float16 Pb[4][16 * 72];   // per-wave roundtrip: [q_local][key or d]
  int blk = blockIdx.x;
  int qt = blk >> 7;          // high bits -> per-CU qt mix for balance
  int bh = blk & 127;
  int h  = bh & 15;
  int b  = bh >> 4;
  int t0 = qt * 64;
  int len = x_lens[b];
  int tid = threadIdx.x;
  int wave = tid >> 6, lane = tid & 63;
  int l15 = lane & 15, quad = lane >> 4;
  size_t plane = (size_t)(b * NHEAD + h) * (T_SEQ * HDIM);
  int qrow = t0 + wave * 16;
  int qabs = qrow + l15;
  const _Float16* Qp = Qg + plane + (size_t)qabs * HDIM + quad * 8;
  half8 qf0 = *(const half8*)Qp;          // B-frag: Q[q=l15][d=quad*8+j]
  half8 qf1 = *(const half8*)(Qp + 32);
  v4f zero = {0.f, 0.f, 0.f, 0.f};
  float m_i = -1e30f, l_i = 0.f;          // per-lane: one q-row
  v4f Ov[4];                              // O^T C-layout: row d=16nt+quad*4+r, col q=l15
#pragma unroll
  for (int nt = 0; nt < 4; ++nt) Ov[nt] = zero;

  int jmaxb = min(t0 + 63, len - 1);
  int ntile = (jmaxb >> 6) + 1;
  int wjmax = min(qrow + 15, len - 1);

  // staging: 16 units of 1KB; wave w handles units w*4..w*4+3
  const _Float16* src[4];
  _Float16* dst[4];
  int strd[4];
#pragma unroll
  for (int i = 0; i < 4; ++i) {
    int u = wave * 4 + i;
    int q = u & 3, hf = (u >> 2) & 1;
    if (u < 8) {
      src[i] = Kk + plane + (size_t)(q * 16 + (lane >> 2)) * HDIM + hf * 32 + (lane & 3) * 8;
      dst[i] = &Ks[hf][0] + q * 512;
      strd[i] = 64 * HDIM;
    } else {
      src[i] = Vt + plane + (size_t)(q * 16 + (lane >> 2)) * T_SEQ + hf * 32 + (lane & 3) * 8;
      dst[i] = &Vs[hf][0] + q * 512;
      strd[i] = 64;
    }
  }

  for (int jt = 0; jt < ntile; ++jt) {
    int j0 = jt * 64;
    __syncthreads();
#pragma unroll
    for (int i = 0; i < 4; ++i) {
      load_lds16(src[i], dst[i]);
      src[i] += strd[i];
    }
    __syncthreads();
    if (j0 <= wjmax) {
      v4f s[4];
#pragma unroll
      for (int nt = 0; nt < 4; ++nt) {
        s[nt] = zero;
        half8 k0 = *(const half8*)&Ks[0][(nt * 16 + l15) * 32 + quad * 8];
        half8 k1 = *(const half8*)&Ks[1][(nt * 16 + l15) * 32 + quad * 8];
        s[nt] = __builtin_amdgcn_mfma_f32_16x16x32_f16(k0, qf0, s[nt], 0, 0, 0);
        s[nt] = __builtin_amdgcn_mfma_f32_16x16x32_f16(k1, qf1, s[nt], 0, 0, 0);
      }
      float mnew = m_i;
      bool full = (j0 + 63 <= qrow) && (j0 + 63 < len);
      if (full) {
#pragma unroll
        for (int nt = 0; nt < 4; ++nt)
#pragma unroll
          for (int r = 0; r < 4; ++r)
            mnew = fmaxf(mnew, s[nt][r]);
      } else {
#pragma unroll
        for (int nt = 0; nt < 4; ++nt) {
#pragma unroll
          for (int r = 0; r < 4; ++r) {
            int key = j0 + nt * 16 + quad * 4 + r;
            float v = (key <= qabs && key < len) ? s[nt][r] : -1e30f;
            s[nt][r] = v;
            mnew = fmaxf(mnew, v);
          }
        }
      }
      mnew = fmaxf(mnew, __shfl_xor(mnew, 16));
      mnew = fmaxf(mnew, __shfl_xor(mnew, 32));
      float alpha = exp2f(m_i - mnew);
      m_i = mnew;
      float rsum = 0.f;
#pragma unroll
      for (int nt = 0; nt < 4; ++nt)
#pragma unroll
        for (int r = 0; r < 4; ++r) {
          float p = exp2f(s[nt][r] - mnew);
          s[nt][r] = p;
          rsum += p;
        }
      rsum += __shfl_xor(rsum, 16);
      rsum += __shfl_xor(rsum, 32);
      l_i = l_i * alpha + rsum;
#pragma unroll
      for (int nt = 0; nt < 4; ++nt)
#pragma unroll
        for (int r = 0; r < 4; ++r) Ov[nt][r] *= alpha;
#pragma unroll
      for (int nt = 0; nt < 4; ++nt) {
        half4h pk;
#pragma unroll
        for (int r = 0; r < 4; ++r) pk[r] = (_Float16)s[nt][r];
        *(half4h*)&Pb[wave][l15 * 72 + nt * 16 + quad * 4] = pk;
      }
      asm volatile("s_waitcnt lgkmcnt(0)" ::: "memory");
      half8 pf0 = *(const half8*)&Pb[wave][l15 * 72 + quad * 8];
      half8 pf1 = *(const half8*)&Pb[wave][l15 * 72 + 32 + quad * 8];
#pragma unroll
      for (int nt = 0; nt < 4; ++nt) {
        half8 v0 = *(const half8*)&Vs[0][(nt * 16 + l15) * 32 + quad * 8];
        half8 v1 = *(const half8*)&Vs[1][(nt * 16 + l15) * 32 + quad * 8];
        Ov[nt] = __builtin_amdgcn_mfma_f32_16x16x32_f16(v0, pf0, Ov[nt], 0, 0, 0);
        Ov[nt] = __builtin_amdgcn_mfma_f32_16x16x32_f16(v1, pf1, Ov[nt], 0, 0, 0);
      }
    }
  }
  // epilogue: O^T regs -> Pb[q][d] -> A-frag layout stores (lane holds O[q=l15][d=quad*8+j])
  float inv = 1.0f / l_i;
#pragma unroll
  for (int nt = 0; nt < 4; ++nt) {
    half4h ok;
#pragma unroll
    for (int r = 0; r < 4; ++r) ok[r] = (_Float16)(Ov[nt][r] * inv);
    *(half4h*)&Pb[wave][l15 * 72 + nt * 16 + quad * 4] = ok;
  }
  asm volatile("s_waitcnt lgkmcnt(0)" ::: "memory");
  half8 o0 = *(const half8*)&Pb[wave][l15 * 72 + quad * 8];        // d 0..31
  half8 o1 = *(const half8*)&Pb[wave][l15 * 72 + 32 + quad * 8];   // d 32..63
  int mt  = (b * T_SEQ + qrow) >> 4;
  int kt0 = h * 2;
  *(half8*)&Afatt[(((size_t)mt * 32 + kt0) * 64 + lane) * 8]     = o0;
  *(half8*)&Afatt[(((size_t)mt * 32 + kt0 + 1) * 64 + lane) * 8] = o1;
}

extern "C" void kernel_launch(void* const* d_in, const int* in_sizes, int n_in,
                              void* d_out, int out_size, void* d_ws, size_t ws_size,
                              hipStream_t stream) {
  const float* x        = (const float*)d_in[0];
  const int*   x_lens   = (const int*)d_in[1];
  const float* ln_gamma = (const float*)d_in[2];
  const float* ln_beta  = (const float*)d_in[3];
  const float* w_qkv    = (const float*)d_in[4];
  const float* b_qkv    = (const float*)d_in[5];
  const float* w_out    = (const float*)d_in[6];
  const float* b_out    = (const float*)d_in[7];
  float* out = (float*)d_out;

  char* w = (char*)d_ws;
  _Float16* xn    = (_Float16*)w; w += (size_t)8192 * 1024 * 2;   // dead after afrag; aliased by Vt
  _Float16* Afq   = (_Float16*)w; w += (size_t)8192 * 1024 * 2;   // xn in A-frag layout
  _Float16* BfQKV = (_Float16*)w; w += (size_t)3072 * 1024 * 2;
  _Float16* BfOut = (_Float16*)w; w += (size_t)1024 * 1024 * 2;
  _Float16* Qd    = (_Float16*)w; w += (size_t)8192 * 1024 * 2;
  _Float16* Kd    = (_Float16*)w; w += (size_t)8192 * 1024 * 2;
  _Float16* Vd    = (_Float16*)w; w += (size_t)8192 * 1024 * 2;
  _Float16* Afatt = (_Float16*)w; w += (size_t)8192 * 1024 * 2;   // attn out, A-frag layout
  _Float16* Vt    = xn;

  fragize_kernel<<<(3072 * 1024 / 8) / 256, 256, 0, stream>>>(w_qkv, BfQKV, 3072, 1024);
  fragize_kernel<<<(1024 * 1024 / 8) / 256, 256, 0, stream>>>(w_out, BfOut, 1024, 1024);
  ln_kernel<<<8192, 256, 0, stream>>>(x, ln_gamma, ln_beta, xn);
  afrag_kernel<<<4096, 256, 0, stream>>>(xn, Afq);
  gemm_kernel<0><<<dim3(8192 / 128, 3072 / 128), 256, 0, stream>>>(
      Afq, BfQKV, b_qkv, 8192, 3072, 1024, nullptr, Qd, Kd, Vd);
  vtrans_kernel<<<dim3(16, 128), 256, 0, stream>>>(Vd, Vt);
  attn_kernel<<<2048, 256, 0, stream>>>(Qd, Kd, Vt, x_lens, Afatt);
  gemm_kernel<1><<<dim3(8192 / 128, 1024 / 128), 256, 0, stream>>>(
      Afatt, BfOut, b_out, 8192, 1024, 1024, out, nullptr, nullptr, nullptr);
}

// Round 8
// 250.180 us; speedup vs baseline: 1.1121x; 1.1121x over previous
//
#include <hip/hip_runtime.h>

#define D_MODEL 1024
#define T_SEQ   1024
#define BATCH   8
#define NHEAD   16
#define HDIM    64

typedef float      v4f   __attribute__((ext_vector_type(4)));
typedef _Float16   half8 __attribute__((ext_vector_type(8)));
typedef _Float16   half4h __attribute__((ext_vector_type(4)));
typedef unsigned int ui4 __attribute__((ext_vector_type(4)));

// async global->LDS, 16B per lane, dest = wave-uniform base + lane*16
__device__ __forceinline__ void load_lds16(const _Float16* g, _Float16* l) {
  __builtin_amdgcn_global_load_lds(
      (const __attribute__((address_space(1))) unsigned int*)g,
      (__attribute__((address_space(3))) unsigned int*)l, 16, 0, 0);
}

// ---------------- LayerNorm (fp32 in) -> fp16 xn ----------------
__global__ __launch_bounds__(256) void ln_kernel(const float* __restrict__ x,
                                                 const float* __restrict__ gamma,
                                                 const float* __restrict__ beta,
                                                 _Float16* __restrict__ xn) {
  int row = blockIdx.x;
  int tid = threadIdx.x;
  const float* xr = x + (size_t)row * D_MODEL;
  v4f xv = *(const v4f*)(xr + tid * 4);
  float s  = xv[0] + xv[1] + xv[2] + xv[3];
  float sq = xv[0]*xv[0] + xv[1]*xv[1] + xv[2]*xv[2] + xv[3]*xv[3];
#pragma unroll
  for (int off = 32; off > 0; off >>= 1) {
    s  += __shfl_xor(s, off);
    sq += __shfl_xor(sq, off);
  }
  __shared__ float ps[4], psq[4];
  int wave = tid >> 6;
  if ((tid & 63) == 0) { ps[wave] = s; psq[wave] = sq; }
  __syncthreads();
  float tot  = ps[0] + ps[1] + ps[2] + ps[3];
  float totq = psq[0] + psq[1] + psq[2] + psq[3];
  float mean = tot * (1.0f / D_MODEL);
  float var  = totq * (1.0f / D_MODEL) - mean * mean;
  float rs   = rsqrtf(var + 1e-5f);
  v4f gv = *(const v4f*)(gamma + tid * 4);
  v4f bv = *(const v4f*)(beta + tid * 4);
  half4h o;
#pragma unroll
  for (int i = 0; i < 4; ++i)
    o[i] = (_Float16)((xv[i] - mean) * rs * gv[i] + bv[i]);
  *(half4h*)(xn + (size_t)row * D_MODEL + tid * 4) = o;
}

// ------- fragize weights: W (K x N fp32) -> Bfrag[nt][kt][lane][8] fp16 -------
__global__ __launch_bounds__(256) void fragize_kernel(const float* __restrict__ W,
                                                      _Float16* __restrict__ Bf,
                                                      int N, int K) {
  int g = blockIdx.x * 256 + threadIdx.x;
  int lane = g & 63, tile = g >> 6;
  int ktiles = K >> 5;
  int kt = tile % ktiles, nt = tile / ktiles;
  int n  = nt * 16 + (lane & 15);
  int k0 = kt * 32 + (lane >> 4) * 8;
  half8 o;
#pragma unroll
  for (int j = 0; j < 8; ++j) o[j] = (_Float16)W[(size_t)(k0 + j) * N + n];
  *(half8*)(Bf + (size_t)g * 8) = o;
}

// ------- batched transpose: Vd (P,1024,64) -> Vt (P,64,1024), fp16 -------
__global__ __launch_bounds__(256) void vtrans_kernel(const _Float16* __restrict__ Vd,
                                                     _Float16* __restrict__ Vt) {
  __shared__ _Float16 tile[64][68];
  int p  = blockIdx.y;
  int t0 = blockIdx.x * 64;
  int tid = threadIdx.x;
  int r = tid >> 3, c = (tid & 7) * 8;
#pragma unroll
  for (int it = 0; it < 2; ++it) {
    int rr = r + it * 32;
    *(ui4*)&tile[rr][c] = *(const ui4*)&Vd[((size_t)p * T_SEQ + t0 + rr) * HDIM + c];
  }
  __syncthreads();
#pragma unroll
  for (int it = 0; it < 2; ++it) {
    int d = r + it * 32;
    half8 o;
#pragma unroll
    for (int j = 0; j < 8; ++j) o[j] = tile[c + j][d];
    *(half8*)&Vt[((size_t)p * HDIM + d) * T_SEQ + t0 + c] = o;
  }
}

// -- 128x128 MFMA GEMM: A dbuf-staged in LDS (1 barrier/ktile), B-frags from L2 --
// MODE 0: epilogue -> Q(B,H,T,64)*(0.125*log2e), K(B,H,T,64), V(B,H,T,64)
// MODE 1: epilogue -> fp32 out + bias
template <int MODE>
__global__ __launch_bounds__(256) void gemm_kernel(
    const _Float16* __restrict__ A, const _Float16* __restrict__ Bfrag,
    const float* __restrict__ bias, int M, int N, int K,
    float* __restrict__ outF,
    _Float16* __restrict__ Qd, _Float16* __restrict__ Kd, _Float16* __restrict__ Vd) {
  __shared__ _Float16 As[2][128 * 32];   // 16 KB, double-buffered A
  int tid = threadIdx.x;
  int wave = tid >> 6, lane = tid & 63;
  int l15 = lane & 15, quad = lane >> 4;
  int wm = (wave & 1) * 64, wn = (wave >> 1) * 64;
  int m0 = blockIdx.x * 128, n0 = blockIdx.y * 128;   // x = M fast: residents share B panel
  v4f zero = {0.f, 0.f, 0.f, 0.f};
  v4f acc[4][4];
#pragma unroll
  for (int i = 0; i < 4; ++i)
#pragma unroll
    for (int j = 0; j < 4; ++j) acc[i][j] = zero;

  int ar0 = tid >> 2;          // per-block row 0..63 (chunk 1: +64)
  int akc = (tid & 3) * 8;
  const _Float16* Ap = A + (size_t)(m0 + ar0) * K + akc;
  _Float16* AsW0 = &As[0][0] + wave * 512;   // lane L lands at +L*16B
  _Float16* AsW1 = &As[1][0] + wave * 512;
  const int ktiles = K >> 5;
  const _Float16* Bp = Bfrag + (size_t)((n0 + wn) >> 4) * ktiles * 512 + lane * 8;

  // prologue: stage kt=0 into buf0
  load_lds16(Ap, AsW0);
  load_lds16(Ap + (size_t)64 * K, AsW0 + 2048);
  for (int kt = 0; kt < ktiles; ++kt) {
    int cur = kt & 1;
    __syncthreads();   // buf[cur] ready (vmcnt drain); prior readers of buf[1-cur] done
    if (kt + 1 < ktiles) {   // prefetch next tile; overlaps this tile's compute
      _Float16* nx = cur ? AsW0 : AsW1;
      load_lds16(Ap + (kt + 1) * 32,                  nx);
      load_lds16(Ap + (kt + 1) * 32 + (size_t)64 * K, nx + 2048);
    }
    half8 bf[4];
#pragma unroll
    for (int ni = 0; ni < 4; ++ni)
      bf[ni] = *(const half8*)(Bp + ((size_t)ni * ktiles + kt) * 512);
    half8 af[4];
#pragma unroll
    for (int i = 0; i < 4; ++i)
      af[i] = *(const half8*)&As[cur][(wm + i * 16 + l15) * 32 + quad * 8];
#pragma unroll
    for (int mi = 0; mi < 4; ++mi)
#pragma unroll
      for (int ni = 0; ni < 4; ++ni)
        acc[mi][ni] = __builtin_amdgcn_mfma_f32_16x16x32_f16(af[mi], bf[ni], acc[mi][ni], 0, 0, 0);
  }
  // epilogue: C layout row=quad*4+r, col=l15
  float bv[4];
#pragma unroll
  for (int ni = 0; ni < 4; ++ni) bv[ni] = bias[n0 + wn + ni * 16 + l15];
#pragma unroll
  for (int mi = 0; mi < 4; ++mi) {
#pragma unroll
    for (int ni = 0; ni < 4; ++ni) {
      int n = n0 + wn + ni * 16 + l15;
#pragma unroll
      for (int r = 0; r < 4; ++r) {
        int m = m0 + wm + mi * 16 + quad * 4 + r;
        float v = acc[mi][ni][r] + bv[ni];
        if (MODE == 1) {
          outF[(size_t)m * N + n] = v;
        } else {
          int b = m >> 10, t = m & 1023;
          int h = (n >> 6) & 15, d = n & 63;
          size_t idx = ((size_t)(b * NHEAD + h) * T_SEQ + t) * HDIM + d;
          // 0.125 * log2(e): softmax runs in exp2 domain
          if (n < 1024)        Qd[idx] = (_Float16)(v * 0.18033688f);
          else if (n < 2048)   Kd[idx] = (_Float16)v;
          else                 Vd[idx] = (_Float16)v;
        }
      }
    }
  }
}

// ------- flash attention, S^T formulation: 64 q-rows/block (4 waves), 64-key tiles ------
// S^T = K Q^T: lane owns ONE q-row (col=l15), 16 keys in regs. O^T = V^T P^T.
__global__ __launch_bounds__(256) void attn_kernel(const _Float16* __restrict__ Qg,
                                                   const _Float16* __restrict__ Kk,
                                                   const _Float16* __restrict__ Vt,
                                                   const int* __restrict__ x_lens,
                                                   _Float16* __restrict__ att) {
  __shared__ _Float16 Ks[2][64 * 32];   // [d-half][key*32 + chunk]
  __shared__ _Float16 Vs[2][64 * 32];   // [key-half][d*32 + chunk]
  __shared__ _Float16 Pb[4][16 * 72];   // per-wave roundtrip: [q_local][key or d]
  int blk = blockIdx.x;
  int qt = blk >> 7;          // high bits -> per-CU qt mix for balance
  int bh = blk & 127;
  int h  = bh & 15;
  int b  = bh >> 4;
  int t0 = qt * 64;
  int len = x_lens[b];
  int tid = threadIdx.x;
  int wave = tid >> 6, lane = tid & 63;
  int l15 = lane & 15, quad = lane >> 4;
  size_t plane = (size_t)(b * NHEAD + h) * (T_SEQ * HDIM);
  int qrow = t0 + wave * 16;
  int qabs = qrow + l15;
  const _Float16* Qp = Qg + plane + (size_t)qabs * HDIM + quad * 8;
  half8 qf0 = *(const half8*)Qp;          // B-frag: Q[q=l15][d=quad*8+j]
  half8 qf1 = *(const half8*)(Qp + 32);
  v4f zero = {0.f, 0.f, 0.f, 0.f};
  float m_i = -1e30f, l_i = 0.f;          // per-lane: one q-row
  v4f Ov[4];                              // O^T C-layout: row d=16nt+quad*4+r, col q=l15
#pragma unroll
  for (int nt = 0; nt < 4; ++nt) Ov[nt] = zero;

  int jmaxb = min(t0 + 63, len - 1);
  int ntile = (jmaxb >> 6) + 1;
  int wjmax = min(qrow + 15, len - 1);

  // staging: 16 units of 1KB; wave w handles units w*4..w*4+3
  const _Float16* src[4];
  _Float16* dst[4];
  int strd[4];
#pragma unroll
  for (int i = 0; i < 4; ++i) {
    int u = wave * 4 + i;
    int q = u & 3, hf = (u >> 2) & 1;
    if (u < 8) {
      src[i] = Kk + plane + (size_t)(q * 16 + (lane >> 2)) * HDIM + hf * 32 + (lane & 3) * 8;
      dst[i] = &Ks[hf][0] + q * 512;
      strd[i] = 64 * HDIM;
    } else {
      src[i] = Vt + plane + (size_t)(q * 16 + (lane >> 2)) * T_SEQ + hf * 32 + (lane & 3) * 8;
      dst[i] = &Vs[hf][0] + q * 512;
      strd[i] = 64;
    }
  }

  for (int jt = 0; jt < ntile; ++jt) {
    int j0 = jt * 64;
    __syncthreads();
#pragma unroll
    for (int i = 0; i < 4; ++i) {
      load_lds16(src[i], dst[i]);
      src[i] += strd[i];
    }
    __syncthreads();
    if (j0 <= wjmax) {
      v4f s[4];
#pragma unroll
      for (int nt = 0; nt < 4; ++nt) {
        s[nt] = zero;
        half8 k0 = *(const half8*)&Ks[0][(nt * 16 + l15) * 32 + quad * 8];
        half8 k1 = *(const half8*)&Ks[1][(nt * 16 + l15) * 32 + quad * 8];
        s[nt] = __builtin_amdgcn_mfma_f32_16x16x32_f16(k0, qf0, s[nt], 0, 0, 0);
        s[nt] = __builtin_amdgcn_mfma_f32_16x16x32_f16(k1, qf1, s[nt], 0, 0, 0);
      }
      float mnew = m_i;
      bool full = (j0 + 63 <= qrow) && (j0 + 63 < len);
      if (full) {
#pragma unroll
        for (int nt = 0; nt < 4; ++nt)
#pragma unroll
          for (int r = 0; r < 4; ++r)
            mnew = fmaxf(mnew, s[nt][r]);
      } else {
#pragma unroll
        for (int nt = 0; nt < 4; ++nt) {
#pragma unroll
          for (int r = 0; r < 4; ++r) {
            int key = j0 + nt * 16 + quad * 4 + r;
            float v = (key <= qabs && key < len) ? s[nt][r] : -1e30f;
            s[nt][r] = v;
            mnew = fmaxf(mnew, v);
          }
        }
      }
      mnew = fmaxf(mnew, __shfl_xor(mnew, 16));
      mnew = fmaxf(mnew, __shfl_xor(mnew, 32));
      float alpha = exp2f(m_i - mnew);
      m_i = mnew;
      float rsum = 0.f;
#pragma unroll
      for (int nt = 0; nt < 4; ++nt)
#pragma unroll
        for (int r = 0; r < 4; ++r) {
          float p = exp2f(s[nt][r] - mnew);
          s[nt][r] = p;
          rsum += p;
        }
      rsum += __shfl_xor(rsum, 16);
      rsum += __shfl_xor(rsum, 32);
      l_i = l_i * alpha + rsum;
#pragma unroll
      for (int nt = 0; nt < 4; ++nt)
#pragma unroll
        for (int r = 0; r < 4; ++r) Ov[nt][r] *= alpha;
#pragma unroll
      for (int nt = 0; nt < 4; ++nt) {
        half4h pk;
#pragma unroll
        for (int r = 0; r < 4; ++r) pk[r] = (_Float16)s[nt][r];
        *(half4h*)&Pb[wave][l15 * 72 + nt * 16 + quad * 4] = pk;
      }
      asm volatile("s_waitcnt lgkmcnt(0)" ::: "memory");
      half8 pf0 = *(const half8*)&Pb[wave][l15 * 72 + quad * 8];
      half8 pf1 = *(const half8*)&Pb[wave][l15 * 72 + 32 + quad * 8];
#pragma unroll
      for (int nt = 0; nt < 4; ++nt) {
        half8 v0 = *(const half8*)&Vs[0][(nt * 16 + l15) * 32 + quad * 8];
        half8 v1 = *(const half8*)&Vs[1][(nt * 16 + l15) * 32 + quad * 8];
        Ov[nt] = __builtin_amdgcn_mfma_f32_16x16x32_f16(v0, pf0, Ov[nt], 0, 0, 0);
        Ov[nt] = __builtin_amdgcn_mfma_f32_16x16x32_f16(v1, pf1, Ov[nt], 0, 0, 0);
      }
    }
  }
  // epilogue: O^T regs -> Pb[q_local][d] -> coalesced row-major stores
  float inv = 1.0f / l_i;
#pragma unroll
  for (int nt = 0; nt < 4; ++nt) {
    half4h ok;
#pragma unroll
    for (int r = 0; r < 4; ++r) ok[r] = (_Float16)(Ov[nt][r] * inv);
    *(half4h*)&Pb[wave][l15 * 72 + nt * 16 + quad * 4] = ok;
  }
  asm volatile("s_waitcnt lgkmcnt(0)" ::: "memory");
  int r0 = lane >> 3, c0 = (lane & 7) * 8;
  half8 o0 = *(const half8*)&Pb[wave][r0 * 72 + c0];
  half8 o1 = *(const half8*)&Pb[wave][(r0 + 8) * 72 + c0];
  *(half8*)&att[((size_t)(b * T_SEQ) + qrow + r0) * D_MODEL + h * HDIM + c0] = o0;
  *(half8*)&att[((size_t)(b * T_SEQ) + qrow + r0 + 8) * D_MODEL + h * HDIM + c0] = o1;
}

extern "C" void kernel_launch(void* const* d_in, const int* in_sizes, int n_in,
                              void* d_out, int out_size, void* d_ws, size_t ws_size,
                              hipStream_t stream) {
  const float* x        = (const float*)d_in[0];
  const int*   x_lens   = (const int*)d_in[1];
  const float* ln_gamma = (const float*)d_in[2];
  const float* ln_beta  = (const float*)d_in[3];
  const float* w_qkv    = (const float*)d_in[4];
  const float* b_qkv    = (const float*)d_in[5];
  const float* w_out    = (const float*)d_in[6];
  const float* b_out    = (const float*)d_in[7];
  float* out = (float*)d_out;

  char* w = (char*)d_ws;
  _Float16* xn    = (_Float16*)w; w += (size_t)8192 * 1024 * 2;   // aliased by Vt after gemm<0>
  _Float16* BfQKV = (_Float16*)w; w += (size_t)3072 * 1024 * 2;
  _Float16* BfOut = (_Float16*)w; w += (size_t)1024 * 1024 * 2;
  _Float16* Qd    = (_Float16*)w; w += (size_t)8192 * 1024 * 2;
  _Float16* Kd    = (_Float16*)w; w += (size_t)8192 * 1024 * 2;
  _Float16* Vd    = (_Float16*)w; w += (size_t)8192 * 1024 * 2;
  _Float16* att   = (_Float16*)w; w += (size_t)8192 * 1024 * 2;
  _Float16* Vt    = xn;   // xn dead after gemm<0>

  fragize_kernel<<<(3072 * 1024 / 8) / 256, 256, 0, stream>>>(w_qkv, BfQKV, 3072, 1024);
  fragize_kernel<<<(1024 * 1024 / 8) / 256, 256, 0, stream>>>(w_out, BfOut, 1024, 1024);
  ln_kernel<<<8192, 256, 0, stream>>>(x, ln_gamma, ln_beta, xn);
  gemm_kernel<0><<<dim3(8192 / 128, 3072 / 128), 256, 0, stream>>>(
      xn, BfQKV, b_qkv, 8192, 3072, 1024, nullptr, Qd, Kd, Vd);
  vtrans_kernel<<<dim3(16, 128), 256, 0, stream>>>(Vd, Vt);
  attn_kernel<<<2048, 256, 0, stream>>>(Qd, Kd, Vt, x_lens, att);
  gemm_kernel<1><<<dim3(8192 / 128, 1024 / 128), 256, 0, stream>>>(
      att, BfOut, b_out, 8192, 1024, 1024, out, nullptr, nullptr, nullptr);
}